// Round 12
// baseline (110.052 us; speedup 1.0000x reference)
//
#include <hip/hip_runtime.h>
#include <math.h>

#define BN  32
#define H   80
#define W   80
#define HW  6400
#define KC  100
#define NCH 90
#define UW  640
#define UHW 409600   // 640*640

static constexpr size_t OUT_MNT   = 0;
static constexpr size_t OUT_KEEP  = (size_t)BN * KC * 4;          // 12800
static constexpr size_t OUT_ENH   = OUT_KEEP + (size_t)BN * KC;   // 16000
static constexpr size_t OUT_CLEAN = OUT_ENH + (size_t)BN * UHW;   // 13123200
static constexpr size_t OUT_ORI   = OUT_CLEAN + (size_t)BN * UHW; // 26230400

#define PI_F 3.14159265358979323846
#define MM_BLOCKS 64      // minmax partial chunks per image
#define CAP 2048          // candidate buffer capacity
#define CLEAN_BLOCKS 320  // 10 bands x 32 images
#define ORI_BLOCKS2 400   // 128 float4-pixels each
#define GATHER_BLOCKS 32  // one per batch (gather + NMS fused)
#define FIN_BLOCKS 1600   // 50 per batch, 2048 float4 each

typedef float vfloat4 __attribute__((ext_vector_type(4)));  // native vec for nt-stores

// ---------------- float <-> order-preserving uint ----------------
__device__ __forceinline__ unsigned enc_f(float f) {
    unsigned u = __float_as_uint(f);
    return (u & 0x80000000u) ? ~u : (u | 0x80000000u);
}
__device__ __forceinline__ float dec_f(unsigned k) {
    return (k & 0x80000000u) ? __uint_as_float(k ^ 0x80000000u) : __uint_as_float(~k);
}
__device__ __forceinline__ unsigned long long shflx(unsigned long long v, int off) {
    unsigned hi = (unsigned)__shfl_xor((int)(unsigned)(v >> 32), off);
    unsigned lo = (unsigned)__shfl_xor((int)(unsigned)(v & 0xffffffffull), off);
    return ((unsigned long long)hi << 32) | lo;
}

// ========== Kernel 1: clean bands (320 blocks) | ori argmax (400 blocks) =====
__global__ __launch_bounds__(512) void k_pre(const float* __restrict__ seg,
                                             const float* __restrict__ ori,
                                             float* __restrict__ cleaned_g,
                                             float* __restrict__ ori_idx) {
    __shared__ __align__(16) char um[16384];
    const int bx = blockIdx.x, tid = threadIdx.x;

    if (bx < CLEAN_BLOCKS) {
        // ---- cleaned mask, one 8-row band (R11-identical numerics) ----
        float* s_in = (float*)um;            // 960 floats
        float* s_h  = (float*)um + 960;      // 960 floats
        const int b = bx / 10, band = bx % 10;
        const int r0 = band * 8 - 2;

        float g[5];
        {
            float s = 0.f;
            #pragma unroll
            for (int i = 0; i < 5; i++) {
                float c = (float)(i - 2);
                g[i] = expf(-(c * c) / 4.5f);
                s += g[i];
            }
            #pragma unroll
            for (int i = 0; i < 5; i++) g[i] /= s;
        }

        for (int i = tid; i < 12 * 80; i += 512) {
            int lr = i / 80, w = i % 80;
            int gr = r0 + lr;
            s_in[i] = (gr >= 0 && gr < H) ? rintf(seg[(size_t)b * HW + gr * W + w]) : 0.f;
        }
        __syncthreads();
        for (int i = tid; i < 12 * 80; i += 512) {
            int lr = i / 80, w = i % 80;
            float acc = 0.f;
            #pragma unroll
            for (int dx = -2; dx <= 2; dx++) {
                int ww = w + dx;
                if (ww >= 0 && ww < W) acc += s_in[lr * 80 + ww] * g[dx + 2];
            }
            s_h[i] = acc;
        }
        __syncthreads();
        for (int i = tid; i < 8 * 80; i += 512) {
            int k = i / 80, w = i % 80;
            float acc = 0.f;
            #pragma unroll
            for (int dy = 0; dy < 5; dy++) acc += s_h[(k + dy) * 80 + w] * g[dy];
            cleaned_g[(size_t)b * HW + (band * 8 + k) * W + w] = rintf(acc);
        }
    } else {
        // ---- orientation argmax: 128 float4-pixels x 4 channel-groups ----
        float4* s_bv = (float4*)um;          // 512 float4 = 8KB
        float4* s_bj = (float4*)um + 512;    // 8KB
        const int grp = tid >> 7, ln = tid & 127;
        const int p4 = (bx - CLEAN_BLOCKS) * 128 + ln;   // < BN*HW/4
        const int b = p4 / (HW / 4), pp = p4 % (HW / 4);
        const float4* o = (const float4*)(ori + (size_t)b * NCH * HW) + pp;
        const int cs = (grp * NCH) >> 2, ce = ((grp + 1) * NCH) >> 2;

        float4 bv = o[(size_t)cs * (HW / 4)];
        float4 bj = make_float4((float)cs, (float)cs, (float)cs, (float)cs);
        for (int j = cs + 1; j < ce; j++) {
            float4 v = o[(size_t)j * (HW / 4)];
            if (v.x > bv.x) { bv.x = v.x; bj.x = (float)j; }
            if (v.y > bv.y) { bv.y = v.y; bj.y = (float)j; }
            if (v.z > bv.z) { bv.z = v.z; bj.z = (float)j; }
            if (v.w > bv.w) { bv.w = v.w; bj.w = (float)j; }
        }
        s_bv[tid] = bv; s_bj[tid] = bj;
        __syncthreads();
        if (grp == 0) {
            #pragma unroll
            for (int g = 1; g < 4; g++) {
                float4 v = s_bv[g * 128 + ln], jx = s_bj[g * 128 + ln];
                if (v.x > bv.x) { bv.x = v.x; bj.x = jx.x; }
                if (v.y > bv.y) { bv.y = v.y; bj.y = jx.y; }
                if (v.z > bv.z) { bv.z = v.z; bj.z = jx.z; }
                if (v.w > bv.w) { bv.w = v.w; bj.w = jx.w; }
            }
            ((float4*)ori_idx)[p4] = bj;
        }
    }
}

// ========== Kernel 2: top-K (32 blocks) | minmax partials (2048 blocks) ======
__global__ __launch_bounds__(512) void k_mid(const float* __restrict__ mscore,
                                             const float* __restrict__ cleaned,
                                             const float* __restrict__ enh,
                                             float* __restrict__ pmin,
                                             float* __restrict__ pmax,
                                             int* __restrict__ ws_idx,
                                             float* __restrict__ ws_val) {
    __shared__ __align__(16) char um[20480];
    __shared__ unsigned long long s_sel[KC];
    __shared__ unsigned s_rm[HW / 32];
    __shared__ int s_cnt[5];
    __shared__ int s_n;
    __shared__ float s_T;
    __shared__ int s_mode;
    __shared__ float smin[8], smax[8];

    const int bx = blockIdx.x, tid = threadIdx.x;
    const int lane = tid & 63;

    if (bx < BN) {
        // ---------------- top-K selection (threshold-compact) ----------------
        unsigned long long* s_cand = (unsigned long long*)um;        // 2048
        unsigned long long* s_red  = (unsigned long long*)um + CAP;  // 512
        const int b = bx;

        if (tid < HW / 32) s_rm[tid] = 0u;
        if (tid < 5) s_cnt[tid] = 0;
        __syncthreads();

        float sc[13];
        #pragma unroll
        for (int j = 0; j < 13; j++) {
            int i = j * 512 + tid;
            sc[j] = (i < HW) ? mscore[(size_t)b * HW + i] * cleaned[(size_t)b * HW + i]
                             : -1.0f;
        }

        int c0 = 0, c1 = 0, c2 = 0, c3 = 0, c4 = 0;
        #pragma unroll
        for (int j = 0; j < 13; j++) {
            float v = sc[j];
            c0 += (v > 0.95f); c1 += (v > 0.9f); c2 += (v > 0.8f);
            c3 += (v > 0.5f);  c4 += (v > 0.0f);
        }
        #pragma unroll
        for (int off = 32; off > 0; off >>= 1) {
            c0 += __shfl_xor(c0, off); c1 += __shfl_xor(c1, off);
            c2 += __shfl_xor(c2, off); c3 += __shfl_xor(c3, off);
            c4 += __shfl_xor(c4, off);
        }
        if (lane == 0) {
            atomicAdd(&s_cnt[0], c0); atomicAdd(&s_cnt[1], c1);
            atomicAdd(&s_cnt[2], c2); atomicAdd(&s_cnt[3], c3);
            atomicAdd(&s_cnt[4], c4);
        }
        __syncthreads();

        if (tid == 0) {
            int n95 = s_cnt[0], n90 = s_cnt[1], n80 = s_cnt[2], n50 = s_cnt[3], n0 = s_cnt[4];
            int mode; float T = 0.f;
            if (n0 < KC)                      { mode = 1; }
            else if (n95 >= KC && n95 <= CAP) { mode = 0; T = 0.95f; }
            else if (n90 >= KC && n90 <= CAP) { mode = 0; T = 0.9f; }
            else if (n80 >= KC && n80 <= CAP) { mode = 0; T = 0.8f; }
            else if (n50 >= KC && n50 <= CAP) { mode = 0; T = 0.5f; }
            else if (n0 <= CAP)               { mode = 0; T = 0.0f; }
            else                              { mode = 2; }
            s_mode = mode; s_T = T; s_n = 0;
        }
        __syncthreads();
        const int mode = s_mode;

        if (mode != 2) {
            const float T = s_T;
            #pragma unroll
            for (int j = 0; j < 13; j++) {
                int i = j * 512 + tid;
                bool take = (mode == 0) ? (sc[j] > T)
                                        : (sc[j] > 0.f || (i < 256 && sc[j] == 0.0f));
                if (take) {
                    int pos = atomicAdd(&s_n, 1);
                    s_cand[pos] = ((unsigned long long)enc_f(sc[j]) << 32) | (unsigned)(HW - i);
                }
            }
            __syncthreads();
            const int n = s_n;
            for (int c = tid; c < n; c += 512) {
                unsigned long long kk = s_cand[c];
                int rank = 0;
                for (int m = 0; m < n; m++) rank += (s_cand[m] > kk) ? 1 : 0;
                if (rank < KC) s_sel[rank] = kk;
            }
            __syncthreads();
        } else {
            for (int k = 0; k < KC; k++) {
                unsigned long long lmax = 0ull;
                #pragma unroll
                for (int j = 0; j < 13; j++) {
                    int i = j * 512 + tid;
                    if (i < HW && sc[j] >= 0.f && !((s_rm[i >> 5] >> (i & 31)) & 1u)) {
                        unsigned long long kk =
                            ((unsigned long long)enc_f(sc[j]) << 32) | (unsigned)(HW - i);
                        if (kk > lmax) lmax = kk;
                    }
                }
                s_red[tid] = lmax;
                __syncthreads();
                for (int off = 256; off > 0; off >>= 1) {
                    if (tid < off) {
                        unsigned long long o = s_red[tid + off];
                        if (o > s_red[tid]) s_red[tid] = o;
                    }
                    __syncthreads();
                }
                if (tid == 0) {
                    unsigned long long wkey = s_red[0];
                    s_sel[k] = wkey;
                    int wi = HW - (int)(wkey & 0xffffffffull);
                    s_rm[wi >> 5] |= 1u << (wi & 31);
                }
                __syncthreads();
            }
        }

        if (tid < KC) {
            unsigned long long e = s_sel[tid];
            ws_idx[(size_t)b * KC + tid] = HW - (int)(e & 0xffffffffull);
            ws_val[(size_t)b * KC + tid] = dec_f((unsigned)(e >> 32));
        }
    } else {
        // ---------------- min/max partials ----------------
        const int mb = bx - BN;                          // [0, BN*MM_BLOCKS)
        const int b = mb >> 6, chunk = mb & 63;
        const float4* e4 = (const float4*)(enh + (size_t)b * UHW);
        const float* cb = cleaned + (size_t)b * HW;

        float vmin = INFINITY, vmax = -INFINITY;
        for (int i = chunk * 512 + tid; i < UHW / 4; i += MM_BLOCKS * 512) {
            float4 v = e4[i];
            int p = i * 4;
            int Y = p / UW, X = p % UW;                  // 4-group in one x8 cell
            float c = cb[(Y >> 3) * W + (X >> 3)];
            float a = v.x * c, bb = v.y * c, cc = v.z * c, dd = v.w * c;
            vmin = fminf(vmin, fminf(fminf(a, bb), fminf(cc, dd)));
            vmax = fmaxf(vmax, fmaxf(fmaxf(a, bb), fmaxf(cc, dd)));
        }
        #pragma unroll
        for (int off = 32; off > 0; off >>= 1) {
            vmin = fminf(vmin, __shfl_xor(vmin, off));
            vmax = fmaxf(vmax, __shfl_xor(vmax, off));
        }
        int wave = tid >> 6;
        if (lane == 0) { smin[wave] = vmin; smax[wave] = vmax; }
        __syncthreads();
        if (tid == 0) {
            float m0 = smin[0], m1 = smax[0];
            #pragma unroll
            for (int wv = 1; wv < 8; wv++) {
                m0 = fminf(m0, smin[wv]);
                m1 = fmaxf(m1, smax[wv]);
            }
            pmin[b * MM_BLOCKS + chunk] = m0;
            pmax[b * MM_BLOCKS + chunk] = m1;
        }
    }
}

// ========== Kernel 3: gather+NMS (32 blocks) | final writes (1600 blocks) ====
__global__ __launch_bounds__(512) void k_fg(const float* __restrict__ enh,
                                            const float* __restrict__ cleaned,
                                            const float* __restrict__ ori_idx,
                                            const float* __restrict__ pmin,
                                            const float* __restrict__ pmax,
                                            const float* __restrict__ mori,
                                            const float* __restrict__ mxo,
                                            const float* __restrict__ myo,
                                            const int* __restrict__ ws_idx,
                                            const float* __restrict__ ws_val,
                                            float* __restrict__ out) {
    const int bx = blockIdx.x, tid = threadIdx.x;

    if (bx < GATHER_BLOCKS) {
        // ---- per-batch gather (8 waves x 13 rounds) then in-block NMS ----
        __shared__ float s_mx[KC], s_my[KC], s_ma[KC], s_mv[KC];
        const int b = bx;
        const int wave = tid >> 6, lane = tid & 63;

        for (int r = 0; r < 13; r++) {
            const int k = r * 8 + wave;
            if (k < KC) {
                const int idx = ws_idx[(size_t)b * KC + k];
                const float* pm = mori + (size_t)b * NCH * HW + idx;
                unsigned long long kk =
                    ((unsigned long long)enc_f(pm[(size_t)lane * HW]) << 32) | (unsigned)(127 - lane);
                if (lane < NCH - 64) {
                    unsigned long long k1 =
                        ((unsigned long long)enc_f(pm[(size_t)(64 + lane) * HW]) << 32)
                        | (unsigned)(127 - (64 + lane));
                    if (k1 > kk) kk = k1;
                }
                unsigned long long kx = 0ull, ky = 0ull;
                if (lane >= 32 && lane < 40)
                    kx = ((unsigned long long)enc_f(mxo[((size_t)b * 8 + (lane - 32)) * HW + idx]) << 32)
                         | (unsigned)(15 - (lane - 32));
                if (lane >= 40 && lane < 48)
                    ky = ((unsigned long long)enc_f(myo[((size_t)b * 8 + (lane - 40)) * HW + idx]) << 32)
                         | (unsigned)(15 - (lane - 40));

                #pragma unroll
                for (int off = 32; off > 0; off >>= 1) {
                    unsigned long long o;
                    o = shflx(kk, off); if (o > kk) kk = o;
                    o = shflx(kx, off); if (o > kx) kx = o;
                    o = shflx(ky, off); if (o > ky) ky = o;
                }

                if (lane == 0) {
                    int ch = 127 - (int)(kk & 0xffffffffull);
                    int xo = 15  - (int)(kx & 0xffffffffull);
                    int yo = 15  - (int)(ky & 0xffffffffull);
                    int rr = idx / W, cc = idx % W;
                    float4 m;
                    m.x = (float)cc * 8.0f + (float)xo;
                    m.y = (float)rr * 8.0f + (float)yo;
                    m.z = ((float)ch * 2.0f - 89.0f) * (float)(PI_F / 180.0);
                    m.w = ws_val[(size_t)b * KC + k];
                    ((float4*)(out + OUT_MNT))[(size_t)b * KC + k] = m;
                    s_mx[k] = m.x; s_my[k] = m.y; s_ma[k] = m.z; s_mv[k] = m.w;
                }
            }
        }
        __syncthreads();

        // ---- sequential NMS on first wave (reference semantics) ----
        if (tid < 64) {
            const int l = tid;
            float x0 = s_mx[l], y0 = s_my[l], a0 = s_ma[l], v0 = s_mv[l];
            bool has1 = (l + 64) < KC;
            float x1 = has1 ? s_mx[l + 64] : 0.f;
            float y1 = has1 ? s_my[l + 64] : 0.f;
            float a1 = has1 ? s_ma[l + 64] : 0.f;
            float v1 = has1 ? s_mv[l + 64] : -1.f;
            int keep0 = (v0 > 0.1f) ? 1 : 0;
            int keep1 = (has1 && v1 > 0.1f) ? 1 : 0;

            for (int i = 0; i < KC; i++) {
                bool hi = i >= 64;
                int src = i & 63;
                float xi = __shfl(hi ? x1 : x0, src);
                float yi = __shfl(hi ? y1 : y0, src);
                float ai = __shfl(hi ? a1 : a0, src);
                int   ki = __shfl(hi ? keep1 : keep0, src);
                if (ki) {
                    if (keep0 && l > i) {
                        float dx = xi - x0, dy = yi - y0;
                        float dist = sqrtf(dx * dx + dy * dy);
                        float ad = fabsf(ai - a0);
                        float am = fminf(ad, (float)(2.0 * PI_F) - ad);
                        if (dist < 16.0f && am < (float)(PI_F / 6.0)) keep0 = 0;
                    }
                    if (keep1 && (l + 64) > i) {
                        float dx = xi - x1, dy = yi - y1;
                        float dist = sqrtf(dx * dx + dy * dy);
                        float ad = fabsf(ai - a1);
                        float am = fminf(ad, (float)(2.0 * PI_F) - ad);
                        if (dist < 16.0f && am < (float)(PI_F / 6.0)) keep1 = 0;
                    }
                }
            }
            out[OUT_KEEP + (size_t)b * KC + l] = (float)keep0;
            if (has1) out[OUT_KEEP + (size_t)b * KC + 64 + l] = (float)keep1;
        }
    } else {
        // ---- final write: 2048 float4 per block (4 per thread) ----
        __shared__ float s_emin, s_emax;
        const int fb = bx - GATHER_BLOCKS;            // [0, FIN_BLOCKS)
        const int b = fb / 50, chunk = fb % 50;
        if (tid < 64) {
            float vmin = pmin[b * MM_BLOCKS + tid];
            float vmax = pmax[b * MM_BLOCKS + tid];
            #pragma unroll
            for (int off = 32; off > 0; off >>= 1) {
                vmin = fminf(vmin, __shfl_xor(vmin, off));
                vmax = fmaxf(vmax, __shfl_xor(vmax, off));
            }
            if (tid == 0) { s_emin = vmin; s_emax = vmax; }
        }
        __syncthreads();
        const float emin = s_emin, emax = s_emax;
        const float inv = 255.0f / (emax - emin + 1e-8f);
        const float4* e4 = (const float4*)(enh + (size_t)b * UHW);
        const float* cb = cleaned + (size_t)b * HW;
        const float* ob = ori_idx + (size_t)b * HW;
        const int base = chunk * 2048;

        #pragma unroll
        for (int it = 0; it < 4; it++) {
            const int i = base + it * 512 + tid;      // < 102400
            float4 e = e4[i];
            int p = i * 4;
            int Y = p / UW, X = p % UW;
            int cidx = (Y >> 3) * W + (X >> 3);
            float c  = cb[cidx];
            float oi = ob[cidx];
            vfloat4 ev;
            ev.x = (e.x * c - emin) * inv;
            ev.y = (e.y * c - emin) * inv;
            ev.z = (e.z * c - emin) * inv;
            ev.w = (e.w * c - emin) * inv;
            float cv = c * 255.0f;
            float ov = (oi * 2.0f - 89.0f) * (float)(PI_F / 180.0) * c;
            vfloat4 cvv = {cv, cv, cv, cv};
            vfloat4 ovv = {ov, ov, ov, ov};
            size_t t4 = (size_t)b * (UHW / 4) + i;
            __builtin_nontemporal_store(ev,  ((vfloat4*)(out + OUT_ENH))   + t4);
            __builtin_nontemporal_store(cvv, ((vfloat4*)(out + OUT_CLEAN)) + t4);
            __builtin_nontemporal_store(ovv, ((vfloat4*)(out + OUT_ORI))   + t4);
        }
    }
}

extern "C" void kernel_launch(void* const* d_in, const int* in_sizes, int n_in,
                              void* d_out, int out_size, void* d_ws, size_t ws_size,
                              hipStream_t stream) {
    const float* seg    = (const float*)d_in[0];
    const float* mscore = (const float*)d_in[1];
    const float* mori   = (const float*)d_in[2];
    const float* mxo    = (const float*)d_in[3];
    const float* myo    = (const float*)d_in[4];
    const float* ori    = (const float*)d_in[5];
    const float* enh    = (const float*)d_in[6];
    float* out = (float*)d_out;

    // workspace layout
    float* cleaned = (float*)d_ws;                         // BN*HW
    float* ori_idx = cleaned + (size_t)BN * HW;            // BN*HW
    float* pmin    = ori_idx + (size_t)BN * HW;            // BN*MM_BLOCKS
    float* pmax    = pmin + (size_t)BN * MM_BLOCKS;        // BN*MM_BLOCKS
    int*   ws_idx  = (int*)(pmax + (size_t)BN * MM_BLOCKS);// BN*KC
    float* ws_val  = (float*)(ws_idx + (size_t)BN * KC);   // BN*KC

    const int nPre = CLEAN_BLOCKS + ORI_BLOCKS2;           // 720
    const int nMid = BN + BN * MM_BLOCKS;                  // 2080
    const int nFG  = GATHER_BLOCKS + FIN_BLOCKS;           // 1632

    k_pre<<<nPre, 512, 0, stream>>>(seg, ori, cleaned, ori_idx);
    k_mid<<<nMid, 512, 0, stream>>>(mscore, cleaned, enh, pmin, pmax, ws_idx, ws_val);
    k_fg<<<nFG, 512, 0, stream>>>(enh, cleaned, ori_idx, pmin, pmax,
                                  mori, mxo, myo, ws_idx, ws_val, out);
}

// Round 13
// 94.066 us; speedup vs baseline: 1.1699x; 1.1699x over previous
//
#include <hip/hip_runtime.h>
#include <math.h>

#define BN  32
#define H   80
#define W   80
#define HW  6400
#define KC  100
#define NCH 90
#define UW  640
#define UHW 409600   // 640*640

static constexpr size_t OUT_MNT   = 0;
static constexpr size_t OUT_KEEP  = (size_t)BN * KC * 4;          // 12800
static constexpr size_t OUT_ENH   = OUT_KEEP + (size_t)BN * KC;   // 16000
static constexpr size_t OUT_CLEAN = OUT_ENH + (size_t)BN * UHW;   // 13123200
static constexpr size_t OUT_ORI   = OUT_CLEAN + (size_t)BN * UHW; // 26230400

#define PI_F 3.14159265358979323846
#define MM_BLOCKS 64      // minmax partial chunks per image
#define CAP 2048          // candidate buffer capacity
#define CLEAN_BLOCKS 320  // 10 bands x 32 images
#define ORI_BLOCKS2 400   // 128 float4-pixels each
#define GAT_BLOCKS 800    // gather blocks in k_fg (4 candidates each)
#define FIN_BLOCKS 12800  // final-write blocks in k_fg (256 thr, 1 float4/thr)

typedef float vfloat4 __attribute__((ext_vector_type(4)));  // native vec for nt-stores

// ---------------- float <-> order-preserving uint ----------------
__device__ __forceinline__ unsigned enc_f(float f) {
    unsigned u = __float_as_uint(f);
    return (u & 0x80000000u) ? ~u : (u | 0x80000000u);
}
__device__ __forceinline__ float dec_f(unsigned k) {
    return (k & 0x80000000u) ? __uint_as_float(k ^ 0x80000000u) : __uint_as_float(~k);
}
__device__ __forceinline__ unsigned long long shflx(unsigned long long v, int off) {
    unsigned hi = (unsigned)__shfl_xor((int)(unsigned)(v >> 32), off);
    unsigned lo = (unsigned)__shfl_xor((int)(unsigned)(v & 0xffffffffull), off);
    return ((unsigned long long)hi << 32) | lo;
}

// ========== Kernel 1: clean bands (320 blocks) | ori argmax (400 blocks) =====
__global__ __launch_bounds__(512) void k_pre(const float* __restrict__ seg,
                                             const float* __restrict__ ori,
                                             float* __restrict__ cleaned_g,
                                             float* __restrict__ ori_idx) {
    __shared__ __align__(16) char um[16384];
    const int bx = blockIdx.x, tid = threadIdx.x;

    if (bx < CLEAN_BLOCKS) {
        // ---- cleaned mask, one 8-row band (R11-identical numerics) ----
        float* s_in = (float*)um;            // 960 floats
        float* s_h  = (float*)um + 960;      // 960 floats
        const int b = bx / 10, band = bx % 10;
        const int r0 = band * 8 - 2;

        float g[5];
        {
            float s = 0.f;
            #pragma unroll
            for (int i = 0; i < 5; i++) {
                float c = (float)(i - 2);
                g[i] = expf(-(c * c) / 4.5f);
                s += g[i];
            }
            #pragma unroll
            for (int i = 0; i < 5; i++) g[i] /= s;
        }

        for (int i = tid; i < 12 * 80; i += 512) {
            int lr = i / 80, w = i % 80;
            int gr = r0 + lr;
            s_in[i] = (gr >= 0 && gr < H) ? rintf(seg[(size_t)b * HW + gr * W + w]) : 0.f;
        }
        __syncthreads();
        for (int i = tid; i < 12 * 80; i += 512) {
            int lr = i / 80, w = i % 80;
            float acc = 0.f;
            #pragma unroll
            for (int dx = -2; dx <= 2; dx++) {
                int ww = w + dx;
                if (ww >= 0 && ww < W) acc += s_in[lr * 80 + ww] * g[dx + 2];
            }
            s_h[i] = acc;
        }
        __syncthreads();
        for (int i = tid; i < 8 * 80; i += 512) {
            int k = i / 80, w = i % 80;
            float acc = 0.f;
            #pragma unroll
            for (int dy = 0; dy < 5; dy++) acc += s_h[(k + dy) * 80 + w] * g[dy];
            cleaned_g[(size_t)b * HW + (band * 8 + k) * W + w] = rintf(acc);
        }
    } else {
        // ---- orientation argmax: 128 float4-pixels x 4 channel-groups ----
        float4* s_bv = (float4*)um;          // 512 float4 = 8KB
        float4* s_bj = (float4*)um + 512;    // 8KB
        const int grp = tid >> 7, ln = tid & 127;
        const int p4 = (bx - CLEAN_BLOCKS) * 128 + ln;   // < BN*HW/4
        const int b = p4 / (HW / 4), pp = p4 % (HW / 4);
        const float4* o = (const float4*)(ori + (size_t)b * NCH * HW) + pp;
        const int cs = (grp * NCH) >> 2, ce = ((grp + 1) * NCH) >> 2;

        float4 bv = o[(size_t)cs * (HW / 4)];
        float4 bj = make_float4((float)cs, (float)cs, (float)cs, (float)cs);
        for (int j = cs + 1; j < ce; j++) {
            float4 v = o[(size_t)j * (HW / 4)];
            if (v.x > bv.x) { bv.x = v.x; bj.x = (float)j; }
            if (v.y > bv.y) { bv.y = v.y; bj.y = (float)j; }
            if (v.z > bv.z) { bv.z = v.z; bj.z = (float)j; }
            if (v.w > bv.w) { bv.w = v.w; bj.w = (float)j; }
        }
        s_bv[tid] = bv; s_bj[tid] = bj;
        __syncthreads();
        if (grp == 0) {
            #pragma unroll
            for (int g = 1; g < 4; g++) {
                float4 v = s_bv[g * 128 + ln], jx = s_bj[g * 128 + ln];
                if (v.x > bv.x) { bv.x = v.x; bj.x = jx.x; }
                if (v.y > bv.y) { bv.y = v.y; bj.y = jx.y; }
                if (v.z > bv.z) { bv.z = v.z; bj.z = jx.z; }
                if (v.w > bv.w) { bv.w = v.w; bj.w = jx.w; }
            }
            ((float4*)ori_idx)[p4] = bj;
        }
    }
}

// ========== Kernel 2: top-K (32 blocks) | minmax partials (2048 blocks) ======
__global__ __launch_bounds__(512) void k_mid(const float* __restrict__ mscore,
                                             const float* __restrict__ cleaned,
                                             const float* __restrict__ enh,
                                             float* __restrict__ pmin,
                                             float* __restrict__ pmax,
                                             int* __restrict__ ws_idx,
                                             float* __restrict__ ws_val) {
    __shared__ __align__(16) char um[20480];
    __shared__ unsigned long long s_sel[KC];
    __shared__ unsigned s_rm[HW / 32];
    __shared__ int s_cnt[5];
    __shared__ int s_n;
    __shared__ float s_T;
    __shared__ int s_mode;
    __shared__ float smin[8], smax[8];

    const int bx = blockIdx.x, tid = threadIdx.x;
    const int lane = tid & 63;

    if (bx < BN) {
        // ---------------- top-K selection (threshold-compact) ----------------
        unsigned long long* s_cand = (unsigned long long*)um;        // 2048
        unsigned long long* s_red  = (unsigned long long*)um + CAP;  // 512
        const int b = bx;

        if (tid < HW / 32) s_rm[tid] = 0u;
        if (tid < 5) s_cnt[tid] = 0;
        __syncthreads();

        float sc[13];
        #pragma unroll
        for (int j = 0; j < 13; j++) {
            int i = j * 512 + tid;
            sc[j] = (i < HW) ? mscore[(size_t)b * HW + i] * cleaned[(size_t)b * HW + i]
                             : -1.0f;
        }

        int c0 = 0, c1 = 0, c2 = 0, c3 = 0, c4 = 0;
        #pragma unroll
        for (int j = 0; j < 13; j++) {
            float v = sc[j];
            c0 += (v > 0.95f); c1 += (v > 0.9f); c2 += (v > 0.8f);
            c3 += (v > 0.5f);  c4 += (v > 0.0f);
        }
        #pragma unroll
        for (int off = 32; off > 0; off >>= 1) {
            c0 += __shfl_xor(c0, off); c1 += __shfl_xor(c1, off);
            c2 += __shfl_xor(c2, off); c3 += __shfl_xor(c3, off);
            c4 += __shfl_xor(c4, off);
        }
        if (lane == 0) {
            atomicAdd(&s_cnt[0], c0); atomicAdd(&s_cnt[1], c1);
            atomicAdd(&s_cnt[2], c2); atomicAdd(&s_cnt[3], c3);
            atomicAdd(&s_cnt[4], c4);
        }
        __syncthreads();

        if (tid == 0) {
            int n95 = s_cnt[0], n90 = s_cnt[1], n80 = s_cnt[2], n50 = s_cnt[3], n0 = s_cnt[4];
            int mode; float T = 0.f;
            if (n0 < KC)                      { mode = 1; }
            else if (n95 >= KC && n95 <= CAP) { mode = 0; T = 0.95f; }
            else if (n90 >= KC && n90 <= CAP) { mode = 0; T = 0.9f; }
            else if (n80 >= KC && n80 <= CAP) { mode = 0; T = 0.8f; }
            else if (n50 >= KC && n50 <= CAP) { mode = 0; T = 0.5f; }
            else if (n0 <= CAP)               { mode = 0; T = 0.0f; }
            else                              { mode = 2; }
            s_mode = mode; s_T = T; s_n = 0;
        }
        __syncthreads();
        const int mode = s_mode;

        if (mode != 2) {
            const float T = s_T;
            #pragma unroll
            for (int j = 0; j < 13; j++) {
                int i = j * 512 + tid;
                bool take = (mode == 0) ? (sc[j] > T)
                                        : (sc[j] > 0.f || (i < 256 && sc[j] == 0.0f));
                if (take) {
                    int pos = atomicAdd(&s_n, 1);
                    s_cand[pos] = ((unsigned long long)enc_f(sc[j]) << 32) | (unsigned)(HW - i);
                }
            }
            __syncthreads();
            const int n = s_n;
            for (int c = tid; c < n; c += 512) {
                unsigned long long kk = s_cand[c];
                int rank = 0;
                for (int m = 0; m < n; m++) rank += (s_cand[m] > kk) ? 1 : 0;
                if (rank < KC) s_sel[rank] = kk;
            }
            __syncthreads();
        } else {
            for (int k = 0; k < KC; k++) {
                unsigned long long lmax = 0ull;
                #pragma unroll
                for (int j = 0; j < 13; j++) {
                    int i = j * 512 + tid;
                    if (i < HW && sc[j] >= 0.f && !((s_rm[i >> 5] >> (i & 31)) & 1u)) {
                        unsigned long long kk =
                            ((unsigned long long)enc_f(sc[j]) << 32) | (unsigned)(HW - i);
                        if (kk > lmax) lmax = kk;
                    }
                }
                s_red[tid] = lmax;
                __syncthreads();
                for (int off = 256; off > 0; off >>= 1) {
                    if (tid < off) {
                        unsigned long long o = s_red[tid + off];
                        if (o > s_red[tid]) s_red[tid] = o;
                    }
                    __syncthreads();
                }
                if (tid == 0) {
                    unsigned long long wkey = s_red[0];
                    s_sel[k] = wkey;
                    int wi = HW - (int)(wkey & 0xffffffffull);
                    s_rm[wi >> 5] |= 1u << (wi & 31);
                }
                __syncthreads();
            }
        }

        if (tid < KC) {
            unsigned long long e = s_sel[tid];
            ws_idx[(size_t)b * KC + tid] = HW - (int)(e & 0xffffffffull);
            ws_val[(size_t)b * KC + tid] = dec_f((unsigned)(e >> 32));
        }
    } else {
        // ---------------- min/max partials ----------------
        const int mb = bx - BN;                          // [0, BN*MM_BLOCKS)
        const int b = mb >> 6, chunk = mb & 63;
        const float4* e4 = (const float4*)(enh + (size_t)b * UHW);
        const float* cb = cleaned + (size_t)b * HW;

        float vmin = INFINITY, vmax = -INFINITY;
        for (int i = chunk * 512 + tid; i < UHW / 4; i += MM_BLOCKS * 512) {
            float4 v = e4[i];
            int p = i * 4;
            int Y = p / UW, X = p % UW;                  // 4-group in one x8 cell
            float c = cb[(Y >> 3) * W + (X >> 3)];
            float a = v.x * c, bb = v.y * c, cc = v.z * c, dd = v.w * c;
            vmin = fminf(vmin, fminf(fminf(a, bb), fminf(cc, dd)));
            vmax = fmaxf(vmax, fmaxf(fmaxf(a, bb), fmaxf(cc, dd)));
        }
        #pragma unroll
        for (int off = 32; off > 0; off >>= 1) {
            vmin = fminf(vmin, __shfl_xor(vmin, off));
            vmax = fmaxf(vmax, __shfl_xor(vmax, off));
        }
        int wave = tid >> 6;
        if (lane == 0) { smin[wave] = vmin; smax[wave] = vmax; }
        __syncthreads();
        if (tid == 0) {
            float m0 = smin[0], m1 = smax[0];
            #pragma unroll
            for (int wv = 1; wv < 8; wv++) {
                m0 = fminf(m0, smin[wv]);
                m1 = fmaxf(m1, smax[wv]);
            }
            pmin[b * MM_BLOCKS + chunk] = m0;
            pmax[b * MM_BLOCKS + chunk] = m1;
        }
    }
}

// ========== Kernel 3: role-split gather (first 800) + final writes ===========
__global__ __launch_bounds__(256) void k_fg(const float* __restrict__ enh,
                                            const float* __restrict__ cleaned,
                                            const float* __restrict__ ori_idx,
                                            const float* __restrict__ pmin,
                                            const float* __restrict__ pmax,
                                            const float* __restrict__ mori,
                                            const float* __restrict__ mxo,
                                            const float* __restrict__ myo,
                                            const int* __restrict__ ws_idx,
                                            const float* __restrict__ ws_val,
                                            float* __restrict__ out) {
    const int bx = blockIdx.x, tid = threadIdx.x;

    if (bx < GAT_BLOCKS) {
        // ---------------- gather: one wave per candidate ----------------
        const int lane = tid & 63;
        const int wid = bx * 4 + (tid >> 6);
        const int b = wid / KC, k = wid % KC;
        const int idx = ws_idx[(size_t)b * KC + k];

        const float* pm = mori + (size_t)b * NCH * HW + idx;
        unsigned long long kk =
            ((unsigned long long)enc_f(pm[(size_t)lane * HW]) << 32) | (unsigned)(127 - lane);
        if (lane < NCH - 64) {
            unsigned long long k1 =
                ((unsigned long long)enc_f(pm[(size_t)(64 + lane) * HW]) << 32)
                | (unsigned)(127 - (64 + lane));
            if (k1 > kk) kk = k1;
        }
        unsigned long long kx = 0ull, ky = 0ull;
        if (lane >= 32 && lane < 40)
            kx = ((unsigned long long)enc_f(mxo[((size_t)b * 8 + (lane - 32)) * HW + idx]) << 32)
                 | (unsigned)(15 - (lane - 32));
        if (lane >= 40 && lane < 48)
            ky = ((unsigned long long)enc_f(myo[((size_t)b * 8 + (lane - 40)) * HW + idx]) << 32)
                 | (unsigned)(15 - (lane - 40));

        #pragma unroll
        for (int off = 32; off > 0; off >>= 1) {
            unsigned long long o;
            o = shflx(kk, off); if (o > kk) kk = o;
            o = shflx(kx, off); if (o > kx) kx = o;
            o = shflx(ky, off); if (o > ky) ky = o;
        }

        if (lane == 0) {
            int ch = 127 - (int)(kk & 0xffffffffull);
            int xo = 15  - (int)(kx & 0xffffffffull);
            int yo = 15  - (int)(ky & 0xffffffffull);
            int r = idx / W, c = idx % W;
            float4 m;
            m.x = (float)c * 8.0f + (float)xo;
            m.y = (float)r * 8.0f + (float)yo;
            m.z = ((float)ch * 2.0f - 89.0f) * (float)(PI_F / 180.0);
            m.w = ws_val[(size_t)b * KC + k];
            ((float4*)(out + OUT_MNT))[(size_t)b * KC + k] = m;
        }
    } else {
        // ---------------- final write: upsample + normalize + 3 outputs ------
        __shared__ float s_emin, s_emax;
        const int fb = bx - GAT_BLOCKS;               // [0, FIN_BLOCKS)
        const int b = fb / 400;                       // 400 blocks per batch
        if (tid < 64) {
            float vmin = pmin[b * MM_BLOCKS + tid];
            float vmax = pmax[b * MM_BLOCKS + tid];
            #pragma unroll
            for (int off = 32; off > 0; off >>= 1) {
                vmin = fminf(vmin, __shfl_xor(vmin, off));
                vmax = fmaxf(vmax, __shfl_xor(vmax, off));
            }
            if (tid == 0) { s_emin = vmin; s_emax = vmax; }
        }
        __syncthreads();

        int t4 = fb * 256 + tid;                      // BN*UHW/4 threads
        int p4 = t4 % (UHW / 4);
        int p = p4 * 4;
        int Y = p / UW, X = p % UW;
        int cidx = b * HW + (Y >> 3) * W + (X >> 3);
        float c  = cleaned[cidx];
        float oi = ori_idx[cidx];
        float emin = s_emin, emax = s_emax;
        float inv = 255.0f / (emax - emin + 1e-8f);

        float4 e = ((const float4*)enh)[t4];
        vfloat4 ev;
        ev.x = (e.x * c - emin) * inv;
        ev.y = (e.y * c - emin) * inv;
        ev.z = (e.z * c - emin) * inv;
        ev.w = (e.w * c - emin) * inv;

        float cv = c * 255.0f;
        float ov = (oi * 2.0f - 89.0f) * (float)(PI_F / 180.0) * c;
        vfloat4 cvv = {cv, cv, cv, cv};
        vfloat4 ovv = {ov, ov, ov, ov};

        __builtin_nontemporal_store(ev,  ((vfloat4*)(out + OUT_ENH))   + t4);
        __builtin_nontemporal_store(cvv, ((vfloat4*)(out + OUT_CLEAN)) + t4);
        __builtin_nontemporal_store(ovv, ((vfloat4*)(out + OUT_ORI))   + t4);
    }
}

// ========== Kernel 4: sequential NMS, one wave per batch, registers ==========
__global__ __launch_bounds__(64) void k_nms(float* __restrict__ out) {
    const int b = blockIdx.x, l = threadIdx.x;
    const float4* mnt = (const float4*)(out + OUT_MNT) + (size_t)b * KC;
    float4 m0 = mnt[l];
    bool has1 = (l + 64) < KC;
    float4 m1 = has1 ? mnt[l + 64] : make_float4(0.f, 0.f, 0.f, -1.f);
    int keep0 = (m0.w > 0.1f) ? 1 : 0;
    int keep1 = (has1 && m1.w > 0.1f) ? 1 : 0;

    for (int i = 0; i < KC; i++) {
        bool hi = i >= 64;
        int src = i & 63;
        float xi = __shfl(hi ? m1.x : m0.x, src);
        float yi = __shfl(hi ? m1.y : m0.y, src);
        float ai = __shfl(hi ? m1.z : m0.z, src);
        int   ki = __shfl(hi ? keep1 : keep0, src);
        if (ki) {
            if (keep0 && l > i) {
                float dx = xi - m0.x, dy = yi - m0.y;
                float dist = sqrtf(dx * dx + dy * dy);
                float ad = fabsf(ai - m0.z);
                float am = fminf(ad, (float)(2.0 * PI_F) - ad);
                if (dist < 16.0f && am < (float)(PI_F / 6.0)) keep0 = 0;
            }
            if (keep1 && (l + 64) > i) {
                float dx = xi - m1.x, dy = yi - m1.y;
                float dist = sqrtf(dx * dx + dy * dy);
                float ad = fabsf(ai - m1.z);
                float am = fminf(ad, (float)(2.0 * PI_F) - ad);
                if (dist < 16.0f && am < (float)(PI_F / 6.0)) keep1 = 0;
            }
        }
    }
    out[OUT_KEEP + (size_t)b * KC + l] = (float)keep0;
    if (has1) out[OUT_KEEP + (size_t)b * KC + 64 + l] = (float)keep1;
}

extern "C" void kernel_launch(void* const* d_in, const int* in_sizes, int n_in,
                              void* d_out, int out_size, void* d_ws, size_t ws_size,
                              hipStream_t stream) {
    const float* seg    = (const float*)d_in[0];
    const float* mscore = (const float*)d_in[1];
    const float* mori   = (const float*)d_in[2];
    const float* mxo    = (const float*)d_in[3];
    const float* myo    = (const float*)d_in[4];
    const float* ori    = (const float*)d_in[5];
    const float* enh    = (const float*)d_in[6];
    float* out = (float*)d_out;

    // workspace layout
    float* cleaned = (float*)d_ws;                         // BN*HW
    float* ori_idx = cleaned + (size_t)BN * HW;            // BN*HW
    float* pmin    = ori_idx + (size_t)BN * HW;            // BN*MM_BLOCKS
    float* pmax    = pmin + (size_t)BN * MM_BLOCKS;        // BN*MM_BLOCKS
    int*   ws_idx  = (int*)(pmax + (size_t)BN * MM_BLOCKS);// BN*KC
    float* ws_val  = (float*)(ws_idx + (size_t)BN * KC);   // BN*KC

    const int nPre = CLEAN_BLOCKS + ORI_BLOCKS2;           // 720
    const int nMid = BN + BN * MM_BLOCKS;                  // 2080
    const int nFG  = GAT_BLOCKS + FIN_BLOCKS;              // 13600

    k_pre<<<nPre, 512, 0, stream>>>(seg, ori, cleaned, ori_idx);
    k_mid<<<nMid, 512, 0, stream>>>(mscore, cleaned, enh, pmin, pmax, ws_idx, ws_val);
    k_fg<<<nFG, 256, 0, stream>>>(enh, cleaned, ori_idx, pmin, pmax,
                                  mori, mxo, myo, ws_idx, ws_val, out);
    k_nms<<<BN, 64, 0, stream>>>(out);
}